// Round 4
// baseline (994.551 us; speedup 1.0000x reference)
//
#include <hip/hip_runtime.h>

#define NUQ 50000
#define NIQ 50000
#define DQ 256
#define NTOT 100000
#define LALPHA 0.2f
#define GPE 782   // fused blocks per entity = ceil(50000/64)

typedef __attribute__((ext_vector_type(8))) __bf16 bf16x8;
typedef __attribute__((ext_vector_type(4))) float floatx4;
typedef __attribute__((ext_vector_type(8))) unsigned short ushort8;

__device__ __forceinline__ float b2f(unsigned short u) {
    unsigned int x = ((unsigned int)u) << 16;
    return __builtin_bit_cast(float, x);
}
__device__ __forceinline__ unsigned short f2b(float f) {
    unsigned int u = __builtin_bit_cast(unsigned int, f);
    u = u + 0x7FFFu + ((u >> 16) & 1u);   // round-to-nearest-even
    return (unsigned short)(u >> 16);
}

#define GLD_LDS16(g, l)                                                        \
    __builtin_amdgcn_global_load_lds(                                          \
        (const __attribute__((address_space(1))) void*)(g),                    \
        (__attribute__((address_space(3))) void*)(l), 16, 0, 0)

// ---------------------------------------------------------------------------
// CSR row_ptr from sorted rows[].
// ---------------------------------------------------------------------------
__global__ __launch_bounds__(256) void build_rowptr(
    const int* __restrict__ rows, int nnz, int* __restrict__ rptr, int n_rows)
{
    int e = blockIdx.x * 256 + threadIdx.x;
    if (e > nnz) return;
    int prev = (e == 0)   ? -1     : rows[e - 1];
    int cur  = (e == nnz) ? n_rows : rows[e];
    for (int r = prev + 1; r <= cur; ++r) rptr[r] = e;
}

// ---------------------------------------------------------------------------
// fp32 -> bf16 (RNE), vectorized. n4 = element_count / 4.
// ---------------------------------------------------------------------------
__global__ __launch_bounds__(256) void cvt_f32_bf16(
    const float* __restrict__ in, unsigned short* __restrict__ out, int n4)
{
    int i = blockIdx.x * 256 + threadIdx.x;
    if (i >= n4) return;
    float4 v = ((const float4*)in)[i];
    ushort4 o;
    o.x = f2b(v.x); o.y = f2b(v.y); o.z = f2b(v.z); o.w = f2b(v.w);
    ((ushort4*)out)[i] = o;
}

// ---------------------------------------------------------------------------
// Build Bt[4][256][512] bf16: Bt[l*2+e][n][k] = (k<256 ? Wside : Wdot)[l][k%256][n]
// ---------------------------------------------------------------------------
__global__ __launch_bounds__(256) void build_bt(
    const float* __restrict__ Ws_u, const float* __restrict__ Wd_u,
    const float* __restrict__ Ws_i, const float* __restrict__ Wd_i,
    unsigned short* __restrict__ Bt)
{
    int idx = blockIdx.x * 256 + threadIdx.x;    // 4*256*512 total
    int k   = idx & 511;
    int n   = (idx >> 9) & 255;
    int buf = idx >> 17;                          // l*2 + e
    int l = buf >> 1, e = buf & 1;
    const float* Wside = e ? Ws_i : Ws_u;
    const float* Wdot  = e ? Wd_i : Wd_u;
    float v = (k < 256) ? Wside[((size_t)l * 256 + k)       * 256 + n]
                        : Wdot [((size_t)l * 256 + (k-256)) * 256 + n];
    Bt[idx] = f2b(v);
}

// ---------------------------------------------------------------------------
// FUSED SpMM + MFMA GEMM + leaky_relu.
//   Block = 64 output rows of one entity.
//   Phase 1: 4 waves x 16 rows each run the v3 gather loop (LI + L*ebs),
//            writing bf16 A-rows [64][512] into XOR-swizzled LDS
//            (idx_sh ^= (row&7)<<3  -> both the contiguous row-write and the
//             strided MFMA frag-read are bank-conflict-free).
//   Phase 2: 64x256 GEMM, BK=32, 4 waves (2x2 of 32x128), A-frags straight
//            from LDS, B single-buffer-staged from L2-resident Bt via
//            global_load_lds (unit-t scheme, verified v2/v3).
//   LDS 64+16=80KB -> 2 blocks/CU: one block's MFMA phase hides under the
//   other's gather phase.
// ---------------------------------------------------------------------------
__global__ __launch_bounds__(256, 2) void fused_spmm_gemm(
    const int* __restrict__ rpA_u, const int* __restrict__ cA_u, const float* __restrict__ vA_u,
    const int* __restrict__ rpB_u, const int* __restrict__ cB_u, const float* __restrict__ vB_u,
    const int* __restrict__ rpA_i, const int* __restrict__ cA_i, const float* __restrict__ vA_i,
    const int* __restrict__ rpB_i, const int* __restrict__ cB_i, const float* __restrict__ vB_i,
    const unsigned short* __restrict__ src,   // [NTOT,256] bf16 (this layer's ebs)
    const unsigned short* __restrict__ Btl,   // layer base: 2 bufs of [256,512]
    float* __restrict__ out,                  // [NTOT,256] fp32 (layer base)
    unsigned short* __restrict__ ebs_next,    // [NTOT,256] bf16 next-layer input
    const int wb)                             // write bf16 copy?
{
    __shared__ unsigned short A_lds[32768];   // 64 KB, [64][512] swizzled
    __shared__ unsigned short Bs[8192];       // 16 KB, unit-t [256 n][32 k]

    const int tid  = threadIdx.x;
    const int lane = tid & 63;
    const int w    = tid >> 6;
    const int wu   = __builtin_amdgcn_readfirstlane(w);
    const int ent  = (blockIdx.x >= GPE) ? 1 : 0;
    const int bx   = blockIdx.x - ent * GPE;
    const int row0 = ent * NUQ + bx * 64;
    const int Mend = ent * NUQ + NUQ;
    const unsigned short* Bt = Btl + (size_t)ent * 131072;

    const int*   rpA = ent ? rpA_i : rpA_u;
    const int*   cAp = ent ? cA_i  : cA_u;
    const float* vAp = ent ? vA_i  : vA_u;
    const int*   rpB = ent ? rpB_i : rpB_u;
    const int*   cBp = ent ? cB_i  : cB_u;
    const float* vBp = ent ? vB_i  : vB_u;

    const int half = lane >> 5;    // which nnz of the current pair
    const int li   = lane & 31;    // dims [li*8, li*8+8)

    // ---------------- Phase 1: gather 16 rows per wave into LDS -------------
    for (int rr = 0; rr < 16; ++rr) {
        const int rl = wu * 16 + rr;            // local row 0..63 (wave-uniform)
        const int r  = row0 + rl;               // global row
        const int widx = (rl * 512 + lane * 8) ^ ((rl & 7) << 3);  // shorts

        if (r >= Mend) {                        // tail: zero the LDS row
            ushort8 z = {0,0,0,0,0,0,0,0};
            *(ushort8*)&A_lds[widx] = z;
            continue;
        }
        const int row = r - ent * NUQ;
        const int sA = rpA[row], eA = rpA[row + 1];
        const int sB = rpB[row], eB = rpB[row + 1];

        float accA[8] = {0.f,0.f,0.f,0.f,0.f,0.f,0.f,0.f};
        float accB[8] = {0.f,0.f,0.f,0.f,0.f,0.f,0.f,0.f};

        int baseA = sA, baseB = sB;
        while (baseA < eA || baseB < eB) {
            int cntA = eA - baseA; cntA = cntA < 0 ? 0 : (cntA > 64 ? 64 : cntA);
            int cntB = eB - baseB; cntB = cntB < 0 ? 0 : (cntB > 64 ? 64 : cntB);
            int mycA = 0; float myvA = 0.f;
            if (lane < cntA) { mycA = cAp[baseA + lane]; myvA = vAp[baseA + lane]; }
            int mycB = 0; float myvB = 0.f;
            if (lane < cntB) { mycB = cBp[baseB + lane]; myvB = vBp[baseB + lane]; }
            const int mx = cntA > cntB ? cntA : cntB;
            #pragma unroll 4
            for (int e = 0; e < mx; e += 2) {
                if (e < cntA) {                       // wave-uniform branch
                    const int   c = __shfl(mycA, e + half, 64);
                    const float v = __shfl(myvA, e + half, 64);
                    const ushort8 s = *(const ushort8*)(src + (size_t)c * DQ + li * 8);
                    #pragma unroll
                    for (int j = 0; j < 8; ++j) accA[j] = fmaf(v, b2f(s[j]), accA[j]);
                }
                if (e < cntB) {
                    const int   c = __shfl(mycB, e + half, 64);
                    const float v = __shfl(myvB, e + half, 64);
                    const ushort8 s = *(const ushort8*)(src + (size_t)c * DQ + li * 8);
                    #pragma unroll
                    for (int j = 0; j < 8; ++j) accB[j] = fmaf(v, b2f(s[j]), accB[j]);
                }
            }
            baseA += 64; baseB += 64;
        }

        #pragma unroll
        for (int j = 0; j < 8; ++j) accA[j] += __shfl_xor(accA[j], 32, 64);
        #pragma unroll
        for (int j = 0; j < 8; ++j) accB[j] += __shfl_xor(accB[j], 32, 64);

        float vo[8];
        if (half == 0) {
            #pragma unroll
            for (int j = 0; j < 8; ++j) vo[j] = accA[j];
        } else {   // L part: multiply by ebs[r] slice
            const ushort8 m = *(const ushort8*)(src + (size_t)r * DQ + li * 8);
            #pragma unroll
            for (int j = 0; j < 8; ++j) vo[j] = accB[j] * b2f(m[j]);
        }
        ushort8 o;
        #pragma unroll
        for (int j = 0; j < 8; ++j) o[j] = f2b(vo[j]);
        *(ushort8*)&A_lds[widx] = o;   // lane*16B within row -> conflict-free
    }

    // ---------------- Phase 2: GEMM, A from LDS -----------------------------
    // B staging: chunk j covers units t = j*256 + tid; wave base = j*2048+w*512.
    const unsigned short* gB[4];
    #pragma unroll
    for (int j = 0; j < 4; ++j) {
        int t = j * 256 + tid;
        int n = ((t >> 6) << 4) | (t & 15);
        gB[j] = Bt + (size_t)n * 512 + ((t >> 4) & 3) * 8;
    }
    const int ldsB = w * 512;       // + j*2048 shorts

    const int lr  = lane >> 4;      // 0..3 (kblk)
    const int lc  = lane & 15;
    const int m_off = (w & 1) * 32;
    const int n_off = (w >> 1) * 128;
    const int gnb   = (w >> 1) * 8; // B 16-col-group base

    floatx4 acc[2][8] = {};

    for (int kt = 0; kt < 16; ++kt) {
        const int ko = kt * 32;     // shorts
        #pragma unroll
        for (int j = 0; j < 4; ++j)
            GLD_LDS16(gB[j] + ko, &Bs[j * 2048 + ldsB]);
        __syncthreads();            // (kt=0: also fences phase-1 LDS writes)

        bf16x8 af[2], bfr[8];
        #pragma unroll
        for (int tm = 0; tm < 2; ++tm) {
            const int m = m_off + tm * 16 + lc;
            af[tm] = *(const bf16x8*)&A_lds[(m * 512 + ko + lr * 8) ^ ((m & 7) << 3)];
        }
        #pragma unroll
        for (int tn = 0; tn < 8; ++tn)
            bfr[tn] = *(const bf16x8*)&Bs[(gnb + tn) * 512 + lr * 128 + lc * 8];

        __syncthreads();            // all reads of Bs done -> next stage may overwrite

        __builtin_amdgcn_s_setprio(1);
        #pragma unroll
        for (int tm = 0; tm < 2; ++tm)
            #pragma unroll
            for (int tn = 0; tn < 8; ++tn)
                acc[tm][tn] = __builtin_amdgcn_mfma_f32_16x16x32_bf16(
                    af[tm], bfr[tn], acc[tm][tn], 0, 0, 0);
        __builtin_amdgcn_s_setprio(0);
    }

    // epilogue: C/D layout col=lane&15, row=(lane>>4)*4+r  [verified m89/m91]
    #pragma unroll
    for (int tm = 0; tm < 2; ++tm) {
        #pragma unroll
        for (int rr = 0; rr < 4; ++rr) {
            const int gr = row0 + m_off + tm * 16 + lr * 4 + rr;
            if (gr >= Mend) continue;
            float*          orow = out      + (size_t)gr * 256;
            unsigned short* brow = ebs_next + (size_t)gr * 256;
            #pragma unroll
            for (int tn = 0; tn < 8; ++tn) {
                const int gc = n_off + tn * 16 + lc;
                float v = acc[tm][tn][rr];
                v = v > 0.f ? v : LALPHA * v;
                orow[gc] = v;
                if (wb) brow[gc] = f2b(v);
            }
        }
    }
}

// ---------------------------------------------------------------------------
extern "C" void kernel_launch(void* const* d_in, const int* in_sizes, int n_in,
                              void* d_out, int out_size, void* d_ws, size_t ws_size,
                              hipStream_t stream) {
    const float* ebs0      = (const float*)d_in[0];
    const float* W_side_u  = (const float*)d_in[1];
    const float* W_dot_u   = (const float*)d_in[2];
    const float* W_side_i  = (const float*)d_in[3];
    const float* W_dot_i   = (const float*)d_in[4];
    const float* LI_vals_u = (const float*)d_in[5];
    const int*   LI_rows_u = (const int*)  d_in[6];
    const int*   LI_cols_u = (const int*)  d_in[7];
    const float* L_vals_u  = (const float*)d_in[8];
    const int*   L_rows_u  = (const int*)  d_in[9];
    const int*   L_cols_u  = (const int*)  d_in[10];
    const float* LI_vals_i = (const float*)d_in[11];
    const int*   LI_rows_i = (const int*)  d_in[12];
    const int*   LI_cols_i = (const int*)  d_in[13];
    const float* L_vals_i  = (const float*)d_in[14];
    const int*   L_rows_i  = (const int*)  d_in[15];
    const int*   L_cols_i  = (const int*)  d_in[16];

    float* out = (float*)d_out;

    // ws layout (bytes):
    //   [0, 51.2M)         ebs0_bf [100000,256] bf16 (layer-1 input)
    //   [51.2M, 102.4M)    ebs1_bf [100000,256] bf16 (layer-2 input)
    //   [102.4M, +1M)      Bt      [4][256][512] bf16
    //   [.., +0.8M)        rptr x4
    unsigned short* ebs0_bf = (unsigned short*)d_ws;
    unsigned short* ebs1_bf = (unsigned short*)((char*)d_ws + 51200000);
    unsigned short* Bt      = (unsigned short*)((char*)d_ws + 102400000);
    int* rp_LI_u = (int*)((char*)d_ws + 103448576);
    int* rp_L_u  = rp_LI_u + 50001;
    int* rp_LI_i = rp_L_u  + 50001;
    int* rp_L_i  = rp_LI_i + 50001;

    const int nnz_LI_u = in_sizes[5];
    const int nnz_L_u  = in_sizes[8];
    const int nnz_LI_i = in_sizes[11];
    const int nnz_L_i  = in_sizes[14];

    dim3 b256(256);
    build_rowptr<<<dim3((nnz_LI_u + 256) / 256), b256, 0, stream>>>(LI_rows_u, nnz_LI_u, rp_LI_u, NUQ);
    build_rowptr<<<dim3((nnz_L_u  + 256) / 256), b256, 0, stream>>>(L_rows_u,  nnz_L_u,  rp_L_u,  NUQ);
    build_rowptr<<<dim3((nnz_LI_i + 256) / 256), b256, 0, stream>>>(LI_rows_i, nnz_LI_i, rp_LI_i, NIQ);
    build_rowptr<<<dim3((nnz_L_i  + 256) / 256), b256, 0, stream>>>(L_rows_i,  nnz_L_i,  rp_L_i,  NIQ);
    build_bt<<<dim3(2048), b256, 0, stream>>>(W_side_u, W_dot_u, W_side_i, W_dot_i, Bt);
    cvt_f32_bf16<<<dim3(25000), b256, 0, stream>>>(ebs0, ebs0_bf, NTOT * DQ / 4);

    dim3 fgrid(2 * GPE);       // 1564 blocks, entity by blockIdx

    for (int l = 0; l < 2; ++l) {
        float* outl = out + (size_t)l * NTOT * DQ;
        const unsigned short* srcl = (l == 0) ? ebs0_bf : ebs1_bf;
        fused_spmm_gemm<<<fgrid, b256, 0, stream>>>(
            rp_LI_u, LI_cols_u, LI_vals_u, rp_L_u, L_cols_u, L_vals_u,
            rp_LI_i, LI_cols_i, LI_vals_i, rp_L_i, L_cols_i, L_vals_i,
            srcl, Bt + (size_t)l * 2 * 131072, outl, ebs1_bf, (l == 0) ? 1 : 0);
    }
}

// Round 5
// 759.582 us; speedup vs baseline: 1.3093x; 1.3093x over previous
//
#include <hip/hip_runtime.h>

#define NUQ 50000
#define NIQ 50000
#define DQ 256
#define NTOT 100000
#define LALPHA 0.2f
#define GPE 782   // gemm blocks per entity = ceil(50000/64)

typedef __attribute__((ext_vector_type(8))) __bf16 bf16x8;
typedef __attribute__((ext_vector_type(4))) float floatx4;
typedef __attribute__((ext_vector_type(8))) unsigned short ushort8;

__device__ __forceinline__ float b2f(unsigned short u) {
    unsigned int x = ((unsigned int)u) << 16;
    return __builtin_bit_cast(float, x);
}
__device__ __forceinline__ unsigned short f2b(float f) {
    unsigned int u = __builtin_bit_cast(unsigned int, f);
    u = u + 0x7FFFu + ((u >> 16) & 1u);   // round-to-nearest-even
    return (unsigned short)(u >> 16);
}

#define GLD_LDS16(g, l)                                                        \
    __builtin_amdgcn_global_load_lds(                                          \
        (const __attribute__((address_space(1))) void*)(g),                    \
        (__attribute__((address_space(3))) void*)(l), 16, 0, 0)

// ---------------------------------------------------------------------------
// CSR row_ptr from sorted rows[].
// ---------------------------------------------------------------------------
__global__ __launch_bounds__(256) void build_rowptr(
    const int* __restrict__ rows, int nnz, int* __restrict__ rptr, int n_rows)
{
    int e = blockIdx.x * 256 + threadIdx.x;
    if (e > nnz) return;
    int prev = (e == 0)   ? -1     : rows[e - 1];
    int cur  = (e == nnz) ? n_rows : rows[e];
    for (int r = prev + 1; r <= cur; ++r) rptr[r] = e;
}

// ---------------------------------------------------------------------------
// fp32 -> bf16 (RNE), vectorized. n4 = element_count / 4.
// ---------------------------------------------------------------------------
__global__ __launch_bounds__(256) void cvt_f32_bf16(
    const float* __restrict__ in, unsigned short* __restrict__ out, int n4)
{
    int i = blockIdx.x * 256 + threadIdx.x;
    if (i >= n4) return;
    float4 v = ((const float4*)in)[i];
    ushort4 o;
    o.x = f2b(v.x); o.y = f2b(v.y); o.z = f2b(v.z); o.w = f2b(v.w);
    ((ushort4*)out)[i] = o;
}

// ---------------------------------------------------------------------------
// Build Bt[4][256][512] bf16: Bt[l*2+e][n][k] = (k<256 ? Wside : Wdot)[l][k%256][n]
// ---------------------------------------------------------------------------
__global__ __launch_bounds__(256) void build_bt(
    const float* __restrict__ Ws_u, const float* __restrict__ Wd_u,
    const float* __restrict__ Ws_i, const float* __restrict__ Wd_i,
    unsigned short* __restrict__ Bt)
{
    int idx = blockIdx.x * 256 + threadIdx.x;    // 4*256*512 total
    int k   = idx & 511;
    int n   = (idx >> 9) & 255;
    int buf = idx >> 17;                          // l*2 + e
    int l = buf >> 1, e = buf & 1;
    const float* Wside = e ? Ws_i : Ws_u;
    const float* Wdot  = e ? Wd_i : Wd_u;
    float v = (k < 256) ? Wside[((size_t)l * 256 + k)       * 256 + n]
                        : Wdot [((size_t)l * 256 + (k-256)) * 256 + n];
    Bt[idx] = f2b(v);
}

// ---------------------------------------------------------------------------
// Fully merged SpMM: one wave per row r, handling BOTH LI (->cols [0,256))
// and L*ebs (->cols [256,512)). [verbatim from R3 -- measured 128 us, at the
// ~6.4 TB/s gather-request ceiling; occupancy-hungry, do NOT fuse]
// ---------------------------------------------------------------------------
__global__ __launch_bounds__(256) void spmm_merged_v3(
    const int* __restrict__ rpA_u, const int* __restrict__ cA_u, const float* __restrict__ vA_u,
    const int* __restrict__ rpB_u, const int* __restrict__ cB_u, const float* __restrict__ vB_u,
    const int* __restrict__ rpA_i, const int* __restrict__ cA_i, const float* __restrict__ vA_i,
    const int* __restrict__ rpB_i, const int* __restrict__ cB_i, const float* __restrict__ vB_i,
    const unsigned short* __restrict__ src,   // [NTOT,256] bf16
    unsigned short* __restrict__ out)         // [NTOT,512] bf16
{
    const int wave = threadIdx.x >> 6;
    const int lane = threadIdx.x & 63;
    const int r    = __builtin_amdgcn_readfirstlane(blockIdx.x * 4 + wave);
    const bool isI = (r >= NUQ);
    const int  row = isI ? (r - NUQ) : r;

    const int*   rpA = isI ? rpA_i : rpA_u;
    const int*   cAp = isI ? cA_i  : cA_u;
    const float* vAp = isI ? vA_i  : vA_u;
    const int*   rpB = isI ? rpB_i : rpB_u;
    const int*   cBp = isI ? cB_i  : cB_u;
    const float* vBp = isI ? vB_i  : vB_u;

    const int sA = rpA[row], eA = rpA[row + 1];
    const int sB = rpB[row], eB = rpB[row + 1];

    const int half = lane >> 5;    // which nnz of the current pair
    const int li   = lane & 31;    // dims [li*8, li*8+8)

    float accA[8] = {0.f, 0.f, 0.f, 0.f, 0.f, 0.f, 0.f, 0.f};
    float accB[8] = {0.f, 0.f, 0.f, 0.f, 0.f, 0.f, 0.f, 0.f};

    int baseA = sA, baseB = sB;
    while (baseA < eA || baseB < eB) {
        int cntA = eA - baseA; cntA = cntA < 0 ? 0 : (cntA > 64 ? 64 : cntA);
        int cntB = eB - baseB; cntB = cntB < 0 ? 0 : (cntB > 64 ? 64 : cntB);
        int mycA = 0; float myvA = 0.f;
        if (lane < cntA) { mycA = cAp[baseA + lane]; myvA = vAp[baseA + lane]; }
        int mycB = 0; float myvB = 0.f;
        if (lane < cntB) { mycB = cBp[baseB + lane]; myvB = vBp[baseB + lane]; }
        const int mx = cntA > cntB ? cntA : cntB;
        #pragma unroll 2
        for (int e = 0; e < mx; e += 2) {
            if (e < cntA) {                       // wave-uniform branch
                const int   c = __shfl(mycA, e + half, 64);
                const float v = __shfl(myvA, e + half, 64);
                const ushort8 s = *(const ushort8*)(src + (size_t)c * DQ + li * 8);
                #pragma unroll
                for (int j = 0; j < 8; ++j) accA[j] = fmaf(v, b2f(s[j]), accA[j]);
            }
            if (e < cntB) {
                const int   c = __shfl(mycB, e + half, 64);
                const float v = __shfl(myvB, e + half, 64);
                const ushort8 s = *(const ushort8*)(src + (size_t)c * DQ + li * 8);
                #pragma unroll
                for (int j = 0; j < 8; ++j) accB[j] = fmaf(v, b2f(s[j]), accB[j]);
            }
        }
        baseA += 64; baseB += 64;
    }

    #pragma unroll
    for (int j = 0; j < 8; ++j) accA[j] += __shfl_xor(accA[j], 32, 64);
    #pragma unroll
    for (int j = 0; j < 8; ++j) accB[j] += __shfl_xor(accB[j], 32, 64);

    float vo[8];
    if (half == 0) {
        #pragma unroll
        for (int j = 0; j < 8; ++j) vo[j] = accA[j];
    } else {   // L part: multiply by ebs[r] slice (merged layout: src row r)
        const ushort8 m = *(const ushort8*)(src + (size_t)r * DQ + li * 8);
        #pragma unroll
        for (int j = 0; j < 8; ++j) vo[j] = accB[j] * b2f(m[j]);
    }
    ushort8 o;
    #pragma unroll
    for (int j = 0; j < 8; ++j) o[j] = f2b(vo[j]);
    *(ushort8*)(out + (size_t)r * 512 + half * 256 + li * 8) = o;
}

// ---------------------------------------------------------------------------
// A-STATIONARY MFMA GEMM + leaky_relu, fused bf16 epilogue.
//   out[r,0:256] = leaky( A[r,0:512] @ Bt[ent]^T ),  ent = r >= 50000
//   Block = 64 rows x 256 cols. The WHOLE 64x512 A-tile is staged into LDS
//   once (64 KB, one coalesced HBM burst, ONE long vmcnt wait per block).
//   K-loop stages only B (16 KB/step) from the L2-resident 256 KB Bt with
//   depth-2 counted vmcnt -- in-loop waits cover only ~200cy L2 latency.
//   Per-step schedule & vmcnt bookkeeping identical to harness-verified v3
//   (4 B-loads/wave/step -> vmcnt(4); vmcnt(0) only at kt=15).
//   LDS unit-t scheme verbatim from v2/v3; A-frag reads gain kt*2048 offset.
//   96 KB LDS -> 1 block/CU: fine for regular prefetched streams.
// ---------------------------------------------------------------------------
__global__ __launch_bounds__(256) void gemm_mfma_leaky_v4(
    const unsigned short* __restrict__ A,     // [NTOT,512] bf16
    const unsigned short* __restrict__ Btl,   // layer base: 2 bufs of [256,512]
    float* __restrict__ out,                  // [NTOT,256] fp32 (layer base)
    unsigned short* __restrict__ ebs,         // [NTOT,256] bf16 next-layer input
    const int wb)                             // write bf16 copy?
{
    __shared__ unsigned short As[32768];      // 64 KB: [16 kt][128 units][8]
    __shared__ unsigned short Bs[2][8192];    // 32 KB: double-buffered B tile

    const int tid  = threadIdx.x;
    const int lane = tid & 63;
    const int w    = tid >> 6;
    const int ent  = (blockIdx.x >= GPE) ? 1 : 0;
    const int bx   = blockIdx.x - ent * GPE;
    const int row0 = ent * NUQ + bx * 64;
    const int Mend = ent * NUQ + NUQ;
    const unsigned short* Bt = Btl + (size_t)ent * 131072;

    // A staging: unit t = tid = w*64 + lane. Wave-uniform LDS base = w*512 shorts.
    const int mA  = ((tid >> 6) << 4) | (tid & 15);
    const int kbA = (tid >> 4) & 3;
    int grs = row0 + mA; if (grs >= Mend) grs = Mend - 1;   // clamp (safe garbage)
    const unsigned short* gA = A + (size_t)grs * 512 + kbA * 8;
    const int ldsA = w * 512;                                // shorts

    // B staging: chunk j covers units t = j*256 + tid; wave base = j*2048+w*512.
    const unsigned short* gB[4];
    #pragma unroll
    for (int j = 0; j < 4; ++j) {
        int t = j * 256 + tid;
        int n = ((t >> 6) << 4) | (t & 15);
        gB[j] = Bt + (size_t)n * 512 + ((t >> 4) & 3) * 8;
    }
    const int ldsB = w * 512;                                // + j*2048 shorts

    const int lr  = lane >> 4;      // 0..3 (kblk)
    const int lc  = lane & 15;
    const int gmb = (w & 1) * 2;    // A 16-row-group base
    const int gnb = (w >> 1) * 8;   // B 16-col-group base

    floatx4 acc[2][8] = {};

    // prologue: stage the ENTIRE A tile (16 chunks) + B tiles 0 and 1.
    // Issue order matters for vmcnt counting: A(16) first, then B0(4), B1(4).
    #pragma unroll
    for (int c = 0; c < 16; ++c)
        GLD_LDS16(gA + c * 32, &As[c * 2048 + ldsA]);
    #pragma unroll
    for (int j = 0; j < 4; ++j) GLD_LDS16(gB[j], &Bs[0][j * 2048 + ldsB]);
    #pragma unroll
    for (int j = 0; j < 4; ++j) GLD_LDS16(gB[j] + 32, &Bs[1][j * 2048 + ldsB]);

    for (int kt = 0; kt < 16; ++kt) {
        const int cur = kt & 1;
        // kt=0: waits A(16)+B0 (leaves B1 pending). kt>0: waits B(kt).
        if (kt < 15) asm volatile("s_waitcnt vmcnt(4)" ::: "memory");
        else         asm volatile("s_waitcnt vmcnt(0)" ::: "memory");
        __builtin_amdgcn_s_barrier();          // all waves' tile-kt staging done

        bf16x8 af[2], bfr[8];
        #pragma unroll
        for (int tm = 0; tm < 2; ++tm)
            af[tm] = *(const bf16x8*)&As[kt * 2048 + (gmb + tm) * 512 + lr * 128 + lc * 8];
        #pragma unroll
        for (int tn = 0; tn < 8; ++tn)
            bfr[tn] = *(const bf16x8*)&Bs[cur][(gnb + tn) * 512 + lr * 128 + lc * 8];

        asm volatile("s_waitcnt lgkmcnt(0)" ::: "memory");
        __builtin_amdgcn_s_barrier();          // all waves done reading Bs[cur]

        if (kt < 14) {                          // stage B tile kt+2 into Bs[cur]
            const int ko = (kt + 2) * 32;
            #pragma unroll
            for (int j = 0; j < 4; ++j)
                GLD_LDS16(gB[j] + ko, &Bs[cur][j * 2048 + ldsB]);
        }

        __builtin_amdgcn_s_setprio(1);
        #pragma unroll
        for (int tm = 0; tm < 2; ++tm)
            #pragma unroll
            for (int tn = 0; tn < 8; ++tn)
                acc[tm][tn] = __builtin_amdgcn_mfma_f32_16x16x32_bf16(
                    af[tm], bfr[tn], acc[tm][tn], 0, 0, 0);
        __builtin_amdgcn_s_setprio(0);
    }

    // epilogue: C/D layout col=lane&15, row=(lane>>4)*4+r  [verified m89/m91]
    const int m_off = (w & 1) * 32;
    const int n_off = (w >> 1) * 128;
    #pragma unroll
    for (int tm = 0; tm < 2; ++tm) {
        #pragma unroll
        for (int rr = 0; rr < 4; ++rr) {
            const int gr = row0 + m_off + tm * 16 + lr * 4 + rr;
            if (gr >= Mend) continue;
            float*          orow = out + (size_t)gr * 256;
            unsigned short* brow = ebs + (size_t)gr * 256;
            #pragma unroll
            for (int tn = 0; tn < 8; ++tn) {
                const int gc = n_off + tn * 16 + lc;
                float v = acc[tm][tn][rr];
                v = v > 0.f ? v : LALPHA * v;
                orow[gc] = v;
                if (wb) brow[gc] = f2b(v);
            }
        }
    }
}

// ---------------------------------------------------------------------------
extern "C" void kernel_launch(void* const* d_in, const int* in_sizes, int n_in,
                              void* d_out, int out_size, void* d_ws, size_t ws_size,
                              hipStream_t stream) {
    const float* ebs0      = (const float*)d_in[0];
    const float* W_side_u  = (const float*)d_in[1];
    const float* W_dot_u   = (const float*)d_in[2];
    const float* W_side_i  = (const float*)d_in[3];
    const float* W_dot_i   = (const float*)d_in[4];
    const float* LI_vals_u = (const float*)d_in[5];
    const int*   LI_rows_u = (const int*)  d_in[6];
    const int*   LI_cols_u = (const int*)  d_in[7];
    const float* L_vals_u  = (const float*)d_in[8];
    const int*   L_rows_u  = (const int*)  d_in[9];
    const int*   L_cols_u  = (const int*)  d_in[10];
    const float* LI_vals_i = (const float*)d_in[11];
    const int*   LI_rows_i = (const int*)  d_in[12];
    const int*   LI_cols_i = (const int*)  d_in[13];
    const float* L_vals_i  = (const float*)d_in[14];
    const int*   L_rows_i  = (const int*)  d_in[15];
    const int*   L_cols_i  = (const int*)  d_in[16];

    float* out = (float*)d_out;

    // ws layout (bytes):
    //   [0, 102.4M)          Abuf    [100000,512] bf16
    //   [102.4M, 153.6M)     ebs_bf  [100000,256] bf16
    //   [153.6M, +1M)        Bt      [4][256][512] bf16
    //   [.., +0.8M)          rptr x4
    unsigned short* Abuf   = (unsigned short*)d_ws;
    unsigned short* ebs_bf = (unsigned short*)((char*)d_ws + 102400000);
    unsigned short* Bt     = (unsigned short*)((char*)d_ws + 153600000);
    int* rp_LI_u = (int*)((char*)d_ws + 154648576);
    int* rp_L_u  = rp_LI_u + 50001;
    int* rp_LI_i = rp_L_u  + 50001;
    int* rp_L_i  = rp_LI_i + 50001;

    const int nnz_LI_u = in_sizes[5];
    const int nnz_L_u  = in_sizes[8];
    const int nnz_LI_i = in_sizes[11];
    const int nnz_L_i  = in_sizes[14];

    dim3 b256(256);
    build_rowptr<<<dim3((nnz_LI_u + 256) / 256), b256, 0, stream>>>(LI_rows_u, nnz_LI_u, rp_LI_u, NUQ);
    build_rowptr<<<dim3((nnz_L_u  + 256) / 256), b256, 0, stream>>>(L_rows_u,  nnz_L_u,  rp_L_u,  NUQ);
    build_rowptr<<<dim3((nnz_LI_i + 256) / 256), b256, 0, stream>>>(LI_rows_i, nnz_LI_i, rp_LI_i, NIQ);
    build_rowptr<<<dim3((nnz_L_i  + 256) / 256), b256, 0, stream>>>(L_rows_i,  nnz_L_i,  rp_L_i,  NIQ);
    build_bt<<<dim3(2048), b256, 0, stream>>>(W_side_u, W_dot_u, W_side_i, W_dot_i, Bt);
    cvt_f32_bf16<<<dim3(25000), b256, 0, stream>>>(ebs0, ebs_bf, NTOT * DQ / 4);

    dim3 sgrid(NTOT / 4);      // 25000 blocks, one wave per row (both matrices)
    dim3 ggrid(2 * GPE);       // 1564 blocks, entity by blockIdx

    for (int l = 0; l < 2; ++l) {
        float* outl = out + (size_t)l * NTOT * DQ;
        spmm_merged_v3<<<sgrid, b256, 0, stream>>>(
            rp_LI_u, LI_cols_u, LI_vals_u, rp_L_u, L_cols_u, L_vals_u,
            rp_LI_i, LI_cols_i, LI_vals_i, rp_L_i, L_cols_i, L_vals_i,
            ebs_bf, Abuf);
        gemm_mfma_leaky_v4<<<ggrid, b256, 0, stream>>>(
            Abuf, Bt + (size_t)l * 2 * 131072, outl, ebs_bf, (l == 0) ? 1 : 0);
    }
}

// Round 6
// 684.361 us; speedup vs baseline: 1.4533x; 1.1099x over previous
//
#include <hip/hip_runtime.h>

#define NUQ 50000
#define NIQ 50000
#define DQ 256
#define NTOT 100000
#define LALPHA 0.2f

typedef __attribute__((ext_vector_type(8))) __bf16 bf16x8;
typedef __attribute__((ext_vector_type(4))) float floatx4;
typedef __attribute__((ext_vector_type(8))) unsigned short ushort8;

__device__ __forceinline__ float b2f(unsigned short u) {
    unsigned int x = ((unsigned int)u) << 16;
    return __builtin_bit_cast(float, x);
}
__device__ __forceinline__ unsigned short f2b(float f) {
    unsigned int u = __builtin_bit_cast(unsigned int, f);
    u = u + 0x7FFFu + ((u >> 16) & 1u);   // round-to-nearest-even
    return (unsigned short)(u >> 16);
}

#define GLD_LDS16(g, l)                                                        \
    __builtin_amdgcn_global_load_lds(                                          \
        (const __attribute__((address_space(1))) void*)(g),                    \
        (__attribute__((address_space(3))) void*)(l), 16, 0, 0)

// ---------------------------------------------------------------------------
// CSR row_ptr from sorted rows[].
// ---------------------------------------------------------------------------
__global__ __launch_bounds__(256) void build_rowptr(
    const int* __restrict__ rows, int nnz, int* __restrict__ rptr, int n_rows)
{
    int e = blockIdx.x * 256 + threadIdx.x;
    if (e > nnz) return;
    int prev = (e == 0)   ? -1     : rows[e - 1];
    int cur  = (e == nnz) ? n_rows : rows[e];
    for (int r = prev + 1; r <= cur; ++r) rptr[r] = e;
}

// ---------------------------------------------------------------------------
// fp32 -> bf16 (RNE), vectorized. n4 = element_count / 4.
// ---------------------------------------------------------------------------
__global__ __launch_bounds__(256) void cvt_f32_bf16(
    const float* __restrict__ in, unsigned short* __restrict__ out, int n4)
{
    int i = blockIdx.x * 256 + threadIdx.x;
    if (i >= n4) return;
    float4 v = ((const float4*)in)[i];
    ushort4 o;
    o.x = f2b(v.x); o.y = f2b(v.y); o.z = f2b(v.z); o.w = f2b(v.w);
    ((ushort4*)out)[i] = o;
}

// ---------------------------------------------------------------------------
// Build Bt as the EXACT LDS image the gemm stages linearly:
//   4 bufs (l*2+e) x 2 n-halves x 65536 shorts.
//   Within a half: S = kt*4096 + g*512 + kblk*128 + lc*8 + j  holds
//   B[n = h*128 + g*16 + lc][k = kt*32 + kblk*8 + j]
//   where B[n][k] = (k<256 ? Wside[l][k][n] : Wdot[l][k-256][n]).
// ---------------------------------------------------------------------------
__global__ __launch_bounds__(256) void build_bt_v5(
    const float* __restrict__ Ws_u, const float* __restrict__ Wd_u,
    const float* __restrict__ Ws_i, const float* __restrict__ Wd_i,
    unsigned short* __restrict__ Bt)
{
    int idx = blockIdx.x * 256 + threadIdx.x;    // 4*131072 total
    int buf = idx >> 17;                          // l*2 + e
    int s2  = idx & 131071;
    int h   = s2 >> 16;
    int S   = s2 & 65535;
    int kt  = S >> 12;
    int g   = (S >> 9) & 7;
    int kb  = (S >> 7) & 3;
    int lc  = (S >> 3) & 15;
    int j   = S & 7;
    int n   = h * 128 + g * 16 + lc;
    int k   = kt * 32 + kb * 8 + j;
    int l = buf >> 1, e = buf & 1;
    const float* Wside = e ? Ws_i : Ws_u;
    const float* Wdot  = e ? Wd_i : Wd_u;
    float v = (k < 256) ? Wside[((size_t)l * 256 + k)       * 256 + n]
                        : Wdot [((size_t)l * 256 + (k-256)) * 256 + n];
    Bt[idx] = f2b(v);
}

// ---------------------------------------------------------------------------
// Fully merged SpMM: one wave per row r, handling BOTH LI (->cols [0,256))
// and L*ebs (->cols [256,512)). [verbatim R3 -- measured 128-129 us across
// 3 rounds; request-path-bound, leave alone]
// ---------------------------------------------------------------------------
__global__ __launch_bounds__(256) void spmm_merged_v3(
    const int* __restrict__ rpA_u, const int* __restrict__ cA_u, const float* __restrict__ vA_u,
    const int* __restrict__ rpB_u, const int* __restrict__ cB_u, const float* __restrict__ vB_u,
    const int* __restrict__ rpA_i, const int* __restrict__ cA_i, const float* __restrict__ vA_i,
    const int* __restrict__ rpB_i, const int* __restrict__ cB_i, const float* __restrict__ vB_i,
    const unsigned short* __restrict__ src,   // [NTOT,256] bf16
    unsigned short* __restrict__ out)         // [NTOT,512] bf16
{
    const int wave = threadIdx.x >> 6;
    const int lane = threadIdx.x & 63;
    const int r    = __builtin_amdgcn_readfirstlane(blockIdx.x * 4 + wave);
    const bool isI = (r >= NUQ);
    const int  row = isI ? (r - NUQ) : r;

    const int*   rpA = isI ? rpA_i : rpA_u;
    const int*   cAp = isI ? cA_i  : cA_u;
    const float* vAp = isI ? vA_i  : vA_u;
    const int*   rpB = isI ? rpB_i : rpB_u;
    const int*   cBp = isI ? cB_i  : cB_u;
    const float* vBp = isI ? vB_i  : vB_u;

    const int sA = rpA[row], eA = rpA[row + 1];
    const int sB = rpB[row], eB = rpB[row + 1];

    const int half = lane >> 5;    // which nnz of the current pair
    const int li   = lane & 31;    // dims [li*8, li*8+8)

    float accA[8] = {0.f, 0.f, 0.f, 0.f, 0.f, 0.f, 0.f, 0.f};
    float accB[8] = {0.f, 0.f, 0.f, 0.f, 0.f, 0.f, 0.f, 0.f};

    int baseA = sA, baseB = sB;
    while (baseA < eA || baseB < eB) {
        int cntA = eA - baseA; cntA = cntA < 0 ? 0 : (cntA > 64 ? 64 : cntA);
        int cntB = eB - baseB; cntB = cntB < 0 ? 0 : (cntB > 64 ? 64 : cntB);
        int mycA = 0; float myvA = 0.f;
        if (lane < cntA) { mycA = cAp[baseA + lane]; myvA = vAp[baseA + lane]; }
        int mycB = 0; float myvB = 0.f;
        if (lane < cntB) { mycB = cBp[baseB + lane]; myvB = vBp[baseB + lane]; }
        const int mx = cntA > cntB ? cntA : cntB;
        #pragma unroll 2
        for (int e = 0; e < mx; e += 2) {
            if (e < cntA) {                       // wave-uniform branch
                const int   c = __shfl(mycA, e + half, 64);
                const float v = __shfl(myvA, e + half, 64);
                const ushort8 s = *(const ushort8*)(src + (size_t)c * DQ + li * 8);
                #pragma unroll
                for (int j = 0; j < 8; ++j) accA[j] = fmaf(v, b2f(s[j]), accA[j]);
            }
            if (e < cntB) {
                const int   c = __shfl(mycB, e + half, 64);
                const float v = __shfl(myvB, e + half, 64);
                const ushort8 s = *(const ushort8*)(src + (size_t)c * DQ + li * 8);
                #pragma unroll
                for (int j = 0; j < 8; ++j) accB[j] = fmaf(v, b2f(s[j]), accB[j]);
            }
        }
        baseA += 64; baseB += 64;
    }

    #pragma unroll
    for (int j = 0; j < 8; ++j) accA[j] += __shfl_xor(accA[j], 32, 64);
    #pragma unroll
    for (int j = 0; j < 8; ++j) accB[j] += __shfl_xor(accB[j], 32, 64);

    float vo[8];
    if (half == 0) {
        #pragma unroll
        for (int j = 0; j < 8; ++j) vo[j] = accA[j];
    } else {   // L part: multiply by ebs[r] slice (merged layout: src row r)
        const ushort8 m = *(const ushort8*)(src + (size_t)r * DQ + li * 8);
        #pragma unroll
        for (int j = 0; j < 8; ++j) vo[j] = accB[j] * b2f(m[j]);
    }
    ushort8 o;
    #pragma unroll
    for (int j = 0; j < 8; ++j) o[j] = f2b(vo[j]);
    *(ushort8*)(out + (size_t)r * 512 + half * 256 + li * 8) = o;
}

// ---------------------------------------------------------------------------
// BARRIER-FREE-K-LOOP MFMA GEMM + leaky_relu, fused bf16 epilogue.
//   Block = 128 rows x 128 cols (one n-half), 8 waves, 512 threads.
//   B-half [128n][512k] = 128 KB staged into LDS ONCE (unit-t layout with kt
//   outermost -- conflict-free frag reads, verbatim scheme from v2/v3).
//   A-frags loaded per-wave DIRECTLY global->reg: lane (lr,lc) reads 16B at
//   (row0+w*16+lc)*512 + kt*32 + lr*8 (exact MFMA A-frag layout). All 16
//   issued before the single barrier -> k-loop is pure ds_read+MFMA, zero
//   VMEM waits, zero barriers.
//   Bijective XCD-chunk swizzle (1564 = 8*195+4) pairs both n-halves of a
//   row-block on the same XCD in adjacent rounds -> 2nd half's A-read = L2 hit.
// ---------------------------------------------------------------------------
__global__ __launch_bounds__(512, 2) void gemm_mfma_leaky_v5(
    const unsigned short* __restrict__ A,     // [NTOT,512] bf16
    const unsigned short* __restrict__ Btl,   // layer base: 2 bufs of 131072
    float* __restrict__ out,                  // [NTOT,256] fp32 (layer base)
    unsigned short* __restrict__ ebs,         // [NTOT,256] bf16 next-layer input
    const int wb)                             // write bf16 copy?
{
    __shared__ unsigned short B_lds[65536];   // 128 KB: [16 kt][8 g][4 kb][16 lc][8 j]

    const int tid  = threadIdx.x;
    const int lane = tid & 63;
    const int w    = tid >> 6;                // wave 0..7

    // bijective XCD-chunk swizzle: nwg = 1564 = 8*195 + 4  [m204]
    const int orig = blockIdx.x;
    const int x    = orig & 7;
    const int kk   = orig >> 3;
    const int wgid = (x < 4 ? x * 196 : 784 + (x - 4) * 195) + kk;

    const int ent  = (wgid >= 782) ? 1 : 0;
    const int loc  = wgid - ent * 782;
    const int rb   = loc >> 1;                // 0..390
    const int nh   = loc & 1;                 // n-half
    const int row0 = ent * NUQ + rb * 128;
    const int Mend = ent * NUQ + NUQ;
    const unsigned short* BtH = Btl + (size_t)ent * 131072 + (size_t)nh * 65536;

    const int lr = lane >> 4;                 // 0..3 (kblk)
    const int lc = lane & 15;

    // ---- stage B-half into LDS: 8192 units of 16B, 16 per thread ----------
    #pragma unroll
    for (int i = 0; i < 16; ++i) {
        const int t0 = i * 512 + w * 64;      // wave-uniform unit base
        GLD_LDS16(BtH + (size_t)(t0 + lane) * 8, &B_lds[t0 * 8]);
    }

    // ---- preload ALL 16 A-frags (global->reg, overlaps B staging) ----------
    int grow = row0 + w * 16 + lc;
    if (grow >= Mend) grow = Mend - 1;        // clamp (garbage, not stored)
    const unsigned short* aRow = A + (size_t)grow * 512 + lr * 8;
    bf16x8 af[16];
    #pragma unroll
    for (int kt = 0; kt < 16; ++kt)
        af[kt] = *(const bf16x8*)(aRow + kt * 32);

    asm volatile("s_waitcnt vmcnt(0)" ::: "memory");
    __syncthreads();                          // the ONLY barrier

    // ---- k-loop: pure LDS + MFMA ------------------------------------------
    floatx4 acc[8] = {};
    #pragma unroll
    for (int kt = 0; kt < 16; ++kt) {
        #pragma unroll
        for (int tn = 0; tn < 8; ++tn) {
            const bf16x8 bfr = *(const bf16x8*)
                &B_lds[kt * 4096 + tn * 512 + lr * 128 + lc * 8];
            acc[tn] = __builtin_amdgcn_mfma_f32_16x16x32_bf16(
                af[kt], bfr, acc[tn], 0, 0, 0);
        }
    }

    // ---- epilogue: C/D layout col=lane&15, row=(lane>>4)*4+rr [m89/m91] ----
    #pragma unroll
    for (int rr = 0; rr < 4; ++rr) {
        const int gr = row0 + w * 16 + lr * 4 + rr;
        if (gr >= Mend) continue;
        float*          orow = out + (size_t)gr * 256;
        unsigned short* brow = ebs + (size_t)gr * 256;
        #pragma unroll
        for (int tn = 0; tn < 8; ++tn) {
            const int gc = nh * 128 + tn * 16 + lc;
            float v = acc[tn][rr];
            v = v > 0.f ? v : LALPHA * v;
            orow[gc] = v;
            if (wb) brow[gc] = f2b(v);
        }
    }
}

// ---------------------------------------------------------------------------
extern "C" void kernel_launch(void* const* d_in, const int* in_sizes, int n_in,
                              void* d_out, int out_size, void* d_ws, size_t ws_size,
                              hipStream_t stream) {
    const float* ebs0      = (const float*)d_in[0];
    const float* W_side_u  = (const float*)d_in[1];
    const float* W_dot_u   = (const float*)d_in[2];
    const float* W_side_i  = (const float*)d_in[3];
    const float* W_dot_i   = (const float*)d_in[4];
    const float* LI_vals_u = (const float*)d_in[5];
    const int*   LI_rows_u = (const int*)  d_in[6];
    const int*   LI_cols_u = (const int*)  d_in[7];
    const float* L_vals_u  = (const float*)d_in[8];
    const int*   L_rows_u  = (const int*)  d_in[9];
    const int*   L_cols_u  = (const int*)  d_in[10];
    const float* LI_vals_i = (const float*)d_in[11];
    const int*   LI_rows_i = (const int*)  d_in[12];
    const int*   LI_cols_i = (const int*)  d_in[13];
    const float* L_vals_i  = (const float*)d_in[14];
    const int*   L_rows_i  = (const int*)  d_in[15];
    const int*   L_cols_i  = (const int*)  d_in[16];

    float* out = (float*)d_out;

    // ws layout (bytes):
    //   [0, 102.4M)          Abuf    [100000,512] bf16
    //   [102.4M, 153.6M)     ebs_bf  [100000,256] bf16
    //   [153.6M, +1M)        Bt      [4][2][65536] bf16 (LDS images)
    //   [.., +0.8M)          rptr x4
    unsigned short* Abuf   = (unsigned short*)d_ws;
    unsigned short* ebs_bf = (unsigned short*)((char*)d_ws + 102400000);
    unsigned short* Bt     = (unsigned short*)((char*)d_ws + 153600000);
    int* rp_LI_u = (int*)((char*)d_ws + 154648576);
    int* rp_L_u  = rp_LI_u + 50001;
    int* rp_LI_i = rp_L_u  + 50001;
    int* rp_L_i  = rp_LI_i + 50001;

    const int nnz_LI_u = in_sizes[5];
    const int nnz_L_u  = in_sizes[8];
    const int nnz_LI_i = in_sizes[11];
    const int nnz_L_i  = in_sizes[14];

    dim3 b256(256);
    build_rowptr<<<dim3((nnz_LI_u + 256) / 256), b256, 0, stream>>>(LI_rows_u, nnz_LI_u, rp_LI_u, NUQ);
    build_rowptr<<<dim3((nnz_L_u  + 256) / 256), b256, 0, stream>>>(L_rows_u,  nnz_L_u,  rp_L_u,  NUQ);
    build_rowptr<<<dim3((nnz_LI_i + 256) / 256), b256, 0, stream>>>(LI_rows_i, nnz_LI_i, rp_LI_i, NIQ);
    build_rowptr<<<dim3((nnz_L_i  + 256) / 256), b256, 0, stream>>>(L_rows_i,  nnz_L_i,  rp_L_i,  NIQ);
    build_bt_v5<<<dim3(2048), b256, 0, stream>>>(W_side_u, W_dot_u, W_side_i, W_dot_i, Bt);
    cvt_f32_bf16<<<dim3(25000), b256, 0, stream>>>(ebs0, ebs_bf, NTOT * DQ / 4);

    dim3 sgrid(NTOT / 4);      // 25000 blocks, one wave per row (both matrices)
    dim3 ggrid(1564);          // 2 ent x 391 rowblocks x 2 n-halves
    dim3 b512(512);

    for (int l = 0; l < 2; ++l) {
        float* outl = out + (size_t)l * NTOT * DQ;
        spmm_merged_v3<<<sgrid, b256, 0, stream>>>(
            rp_LI_u, LI_cols_u, LI_vals_u, rp_L_u, L_cols_u, L_vals_u,
            rp_LI_i, LI_cols_i, LI_vals_i, rp_L_i, L_cols_i, L_vals_i,
            ebs_bf, Abuf);
        gemm_mfma_leaky_v5<<<ggrid, b512, 0, stream>>>(
            Abuf, Bt + (size_t)l * 2 * 131072, outl, ebs_bf, (l == 0) ? 1 : 0);
    }
}